// Round 1
// baseline (607.410 us; speedup 1.0000x reference)
//
#include <hip/hip_runtime.h>
#include <math.h>

// ---------------------------------------------------------------------------
// Problem constants
// ---------------------------------------------------------------------------
#define B_   4
#define CIN_ 64
#define COUT_ 32
#define K_   3
#define MOD_ 128
#define BANK_ 4
#define D_   32           // input spatial
#define VOX_ 32768        // 32^3
#define UPD_ 64           // output spatial
#define UPVOX_ 262144     // 64^3
#define TAPS_ 27
#define EPS_ 1e-8f

// Workspace layout (in floats)
#define WS_ALPHA 0                         // 16 floats  [b][n]
#define WS_S     16                        // 256 floats [b][i]
#define WS_W     512                       // 221184 floats [b][oc4][i][t][ol8]
#define WS_Y     221696                    // 4*32*32768 floats, conv output

// Output layout (floats in d_out)
#define OUT_YUP  0                         // 4*32*64^3 = 33554432
#define OUT_VOX  33554432                  // 4*64^3   = 1048576

// ---------------------------------------------------------------------------
// Kernel 1: alpha = softmax(style@sel_w.T + sel_b); s = style@affine_w.T + affine_b
// ---------------------------------------------------------------------------
__global__ __launch_bounds__(256) void k_style(
    const float* __restrict__ style,     // [4][128]
    const float* __restrict__ affine_w,  // [64][128]
    const float* __restrict__ affine_b,  // [64]
    const float* __restrict__ sel_w,     // [4][128]
    const float* __restrict__ sel_b,     // [4]
    float* __restrict__ ws) {
  __shared__ float lg[16];
  const int tid = threadIdx.x;

  if (tid < 16) {
    const int b = tid >> 2, n = tid & 3;
    float l = sel_b[n];
    for (int k = 0; k < MOD_; ++k) l += style[b * MOD_ + k] * sel_w[n * MOD_ + k];
    lg[tid] = l;
  }
  __syncthreads();
  if (tid < 16) {
    const int b = tid >> 2;
    const float m = fmaxf(fmaxf(lg[b * 4 + 0], lg[b * 4 + 1]),
                          fmaxf(lg[b * 4 + 2], lg[b * 4 + 3]));
    float den = 0.f;
    for (int j = 0; j < 4; ++j) den += expf(lg[b * 4 + j] - m);
    ws[WS_ALPHA + tid] = expf(lg[tid] - m) / den;
  }
  // s[b][i], tid -> b=tid/64, i=tid%64
  {
    const int b = tid >> 6, i = tid & 63;
    float v = affine_b[i];
    for (int k = 0; k < MOD_; ++k) v += style[b * MOD_ + k] * affine_w[i * MOD_ + k];
    ws[WS_S + tid] = v;
  }
}

// ---------------------------------------------------------------------------
// Kernel 2: per (b,o): w = (sum_n alpha*bank) * s; demod; store as
// ws_w[b*55296 + (o/8)*13824 + (i*27+t)*8 + (o%8)]
// ---------------------------------------------------------------------------
__global__ __launch_bounds__(256) void k_weights(
    const float* __restrict__ bank,   // [4][32][64][27]
    const float* __restrict__ ws_in,  // alpha + s
    float* __restrict__ ws_w) {
  const int b = blockIdx.x >> 5;
  const int o = blockIdx.x & 31;
  const int tid = threadIdx.x;
  __shared__ float red[256];

  float al[4];
#pragma unroll
  for (int n = 0; n < 4; ++n) al[n] = ws_in[WS_ALPHA + b * 4 + n];
  const float* sB = ws_in + WS_S + b * 64;

  float wv[7];
  float ss = 0.f;
#pragma unroll
  for (int r = 0; r < 7; ++r) {
    const int e = tid + r * 256;
    float v = 0.f;
    if (e < CIN_ * TAPS_) {
      const int i = e / TAPS_;
      const int t = e - i * TAPS_;
      const int base = ((0 * COUT_ + o) * CIN_ + i) * TAPS_ + t;
      float bw = 0.f;
#pragma unroll
      for (int n = 0; n < 4; ++n)
        bw += al[n] * bank[base + n * (COUT_ * CIN_ * TAPS_)];
      v = bw * sB[i];
    }
    wv[r] = v;
    ss += v * v;
  }
  red[tid] = ss;
  __syncthreads();
  for (int st = 128; st > 0; st >>= 1) {
    if (tid < st) red[tid] += red[tid + st];
    __syncthreads();
  }
  const float demod = rsqrtf(red[0] + EPS_);

  const int oc = o >> 3, ol = o & 7;
  float* dst = ws_w + b * (4 * 13824) + oc * 13824 + ol;
#pragma unroll
  for (int r = 0; r < 7; ++r) {
    const int e = tid + r * 256;
    if (e < CIN_ * TAPS_) dst[e * 8] = wv[r] * demod;
  }
}

// ---------------------------------------------------------------------------
// Kernel 3: 3D conv, pad 1. Block = (quarter-z-plane 256 voxels, oc-chunk, b).
// Weights for 8 output channels staged in LDS as [i][tap][ol8] -> wave-uniform
// float4 broadcasts.
// ---------------------------------------------------------------------------
__global__ __launch_bounds__(256) void k_conv(
    const float* __restrict__ x,     // [4][64][32][32][32]
    const float* __restrict__ ws_w,  // staged weights
    float* __restrict__ ws_y) {      // [4][32][32768]
  __shared__ float wl[13824];        // 8 oc * 64 i * 27 taps
  const int b = blockIdx.z;
  const int oc = blockIdx.y;
  const int tid = threadIdx.x;

  {
    const float4* src = (const float4*)(ws_w + b * (4 * 13824) + oc * 13824);
    float4* dst = (float4*)wl;
    for (int j = tid; j < 13824 / 4; j += 256) dst[j] = src[j];
  }
  __syncthreads();

  const int v = blockIdx.x * 256 + tid;
  const int z = v >> 10;
  const int y0 = (v >> 5) & 31;
  const int x0 = v & 31;

  float acc0 = 0.f, acc1 = 0.f, acc2 = 0.f, acc3 = 0.f;
  float acc4 = 0.f, acc5 = 0.f, acc6 = 0.f, acc7 = 0.f;

  const float* xb = x + b * (CIN_ * VOX_);
  for (int i = 0; i < CIN_; ++i) {
    const float* xc = xb + i * VOX_;
    const float* wr = wl + i * (TAPS_ * 8);
#pragma unroll
    for (int dz = 0; dz < 3; ++dz) {
      const int zz = z + dz - 1;
      const bool zok = (unsigned)zz < 32u;
#pragma unroll
      for (int dy = 0; dy < 3; ++dy) {
        const int yy = y0 + dy - 1;
        const bool yok = (unsigned)yy < 32u;
#pragma unroll
        for (int dx = 0; dx < 3; ++dx) {
          const int xx = x0 + dx - 1;
          const bool xok = (unsigned)xx < 32u;
          const float msk = (zok && yok && xok) ? 1.0f : 0.0f;
          const float xv = xc[(zz & 31) * 1024 + (yy & 31) * 32 + (xx & 31)] * msk;
          const float* wp = wr + ((dz * 3 + dy) * 3 + dx) * 8;
          const float4 wa = *(const float4*)wp;
          const float4 wb = *(const float4*)(wp + 4);
          acc0 = fmaf(xv, wa.x, acc0);
          acc1 = fmaf(xv, wa.y, acc1);
          acc2 = fmaf(xv, wa.z, acc2);
          acc3 = fmaf(xv, wa.w, acc3);
          acc4 = fmaf(xv, wb.x, acc4);
          acc5 = fmaf(xv, wb.y, acc5);
          acc6 = fmaf(xv, wb.z, acc6);
          acc7 = fmaf(xv, wb.w, acc7);
        }
      }
    }
  }

  float* yo = ws_y + (b * COUT_ + oc * 8) * VOX_ + v;
  yo[0 * VOX_] = acc0;
  yo[1 * VOX_] = acc1;
  yo[2 * VOX_] = acc2;
  yo[3 * VOX_] = acc3;
  yo[4 * VOX_] = acc4;
  yo[5 * VOX_] = acc5;
  yo[6 * VOX_] = acc6;
  yo[7 * VOX_] = acc7;
}

// ---------------------------------------------------------------------------
// Kernel 4: trilinear 2x upsample (align_corners=False) + 1x1x1 vox head.
// One thread per up-voxel; loops over 32 channels, accumulating the vox dot.
// ---------------------------------------------------------------------------
__global__ __launch_bounds__(256) void k_up(
    const float* __restrict__ ws_y,   // [4][32][32768]
    const float* __restrict__ vox_w,  // [1][32]
    const float* __restrict__ vox_b,  // [1]
    float* __restrict__ out) {
  const int b = blockIdx.y;
  const int v = blockIdx.x * 256 + threadIdx.x;  // 0..262143
  const int z = v >> 12;
  const int y = (v >> 6) & 63;
  const int x = v & 63;

  const float sz = fmaxf(z * 0.5f - 0.25f, 0.f);
  const int z0 = (int)sz;
  const float wz = sz - (float)z0;
  const int z1 = min(z0 + 1, 31);

  const float sy = fmaxf(y * 0.5f - 0.25f, 0.f);
  const int yy0 = (int)sy;
  const float wy = sy - (float)yy0;
  const int yy1 = min(yy0 + 1, 31);

  const float sx = fmaxf(x * 0.5f - 0.25f, 0.f);
  const int x0 = (int)sx;
  const float wx = sx - (float)x0;
  const int x1 = min(x0 + 1, 31);

  const int r00 = z0 * 1024 + yy0 * 32;
  const int r01 = z0 * 1024 + yy1 * 32;
  const int r10 = z1 * 1024 + yy0 * 32;
  const int r11 = z1 * 1024 + yy1 * 32;

  const float w000 = (1.f - wz) * (1.f - wy) * (1.f - wx);
  const float w001 = (1.f - wz) * (1.f - wy) * wx;
  const float w010 = (1.f - wz) * wy * (1.f - wx);
  const float w011 = (1.f - wz) * wy * wx;
  const float w100 = wz * (1.f - wy) * (1.f - wx);
  const float w101 = wz * (1.f - wy) * wx;
  const float w110 = wz * wy * (1.f - wx);
  const float w111 = wz * wy * wx;

  const float* yb = ws_y + b * (COUT_ * VOX_);
  float* yup = out + OUT_YUP + b * (COUT_ * UPVOX_) + v;
  const float vb = vox_b[0];

  float outacc = 0.f;
  for (int o = 0; o < COUT_; ++o) {
    const float* yc = yb + o * VOX_;
    const float val =
        w000 * yc[r00 + x0] + w001 * yc[r00 + x1] +
        w010 * yc[r01 + x0] + w011 * yc[r01 + x1] +
        w100 * yc[r10 + x0] + w101 * yc[r10 + x1] +
        w110 * yc[r11 + x0] + w111 * yc[r11 + x1];
    yup[o * UPVOX_] = val;
    outacc = fmaf(vox_w[o], val, outacc);
  }
  out[OUT_VOX + b * UPVOX_ + v] = outacc + vb;
}

// ---------------------------------------------------------------------------
extern "C" void kernel_launch(void* const* d_in, const int* in_sizes, int n_in,
                              void* d_out, int out_size, void* d_ws, size_t ws_size,
                              hipStream_t stream) {
  const float* x        = (const float*)d_in[0];
  const float* style    = (const float*)d_in[1];
  const float* bank     = (const float*)d_in[2];
  const float* affine_w = (const float*)d_in[3];
  const float* affine_b = (const float*)d_in[4];
  const float* sel_w    = (const float*)d_in[5];
  const float* sel_b    = (const float*)d_in[6];
  const float* vox_w    = (const float*)d_in[7];
  const float* vox_b    = (const float*)d_in[8];
  float* out = (float*)d_out;
  float* ws  = (float*)d_ws;

  k_style<<<1, 256, 0, stream>>>(style, affine_w, affine_b, sel_w, sel_b, ws);
  k_weights<<<128, 256, 0, stream>>>(bank, ws, ws + WS_W);
  k_conv<<<dim3(VOX_ / 256, 4, B_), 256, 0, stream>>>(x, ws + WS_W, ws + WS_Y);
  k_up<<<dim3(UPVOX_ / 256, B_), 256, 0, stream>>>(ws + WS_Y, vox_w, vox_b, out);
}

// Round 2
// 299.455 us; speedup vs baseline: 2.0284x; 2.0284x over previous
//
#include <hip/hip_runtime.h>
#include <math.h>

// ---------------------------------------------------------------------------
// Problem constants
// ---------------------------------------------------------------------------
#define B_   4
#define CIN_ 64
#define COUT_ 32
#define MOD_ 128
#define VOX_ 32768        // 32^3
#define UPVOX_ 262144     // 64^3
#define TAPS_ 27
#define EPS_ 1e-8f

#define HALO_ 816         // 4z * 6y * 34x halo voxels per workgroup tile
#define CHUNK_HALVES_ 13824  // 16 i * 27 taps * 32 oc

// Workspace layout (in floats)
#define WS_ALPHA 0        // 16 floats  [b][n]
#define WS_S     16       // 256 floats [b][i]
#define WS_WF16  512      // f16 weights: 4b * 55296 halves = 442368 B (16B-aligned)
#define WS_Y     111104   // 4*32*32768 floats, conv output

// Output layout (floats in d_out)
#define OUT_YUP  0
#define OUT_VOX  33554432

typedef _Float16 half8 __attribute__((ext_vector_type(8)));
typedef float floatx16 __attribute__((ext_vector_type(16)));

// ---------------------------------------------------------------------------
// Kernel 1: alpha = softmax(style@sel_w.T + sel_b); s = style@affine_w.T + affine_b
// ---------------------------------------------------------------------------
__global__ __launch_bounds__(256) void k_style(
    const float* __restrict__ style,     // [4][128]
    const float* __restrict__ affine_w,  // [64][128]
    const float* __restrict__ affine_b,  // [64]
    const float* __restrict__ sel_w,     // [4][128]
    const float* __restrict__ sel_b,     // [4]
    float* __restrict__ ws) {
  __shared__ float lg[16];
  const int tid = threadIdx.x;

  if (tid < 16) {
    const int b = tid >> 2, n = tid & 3;
    float l = sel_b[n];
    for (int k = 0; k < MOD_; ++k) l += style[b * MOD_ + k] * sel_w[n * MOD_ + k];
    lg[tid] = l;
  }
  __syncthreads();
  if (tid < 16) {
    const int b = tid >> 2;
    const float m = fmaxf(fmaxf(lg[b * 4 + 0], lg[b * 4 + 1]),
                          fmaxf(lg[b * 4 + 2], lg[b * 4 + 3]));
    float den = 0.f;
    for (int j = 0; j < 4; ++j) den += expf(lg[b * 4 + j] - m);
    ws[WS_ALPHA + tid] = expf(lg[tid] - m) / den;
  }
  {
    const int b = tid >> 6, i = tid & 63;
    float v = affine_b[i];
    for (int k = 0; k < MOD_; ++k) v += style[b * MOD_ + k] * affine_w[i * MOD_ + k];
    ws[WS_S + tid] = v;
  }
}

// ---------------------------------------------------------------------------
// Kernel 2: per (b,o): w = (sum_n alpha*bank) * s; demod; convert to f16 and
// store in MFMA A-fragment order: wf16[b][chunk c][tap t][half h][oc][j]
// where input channel i = c*16 + h*8 + j.
// ---------------------------------------------------------------------------
__global__ __launch_bounds__(256) void k_weights(
    const float* __restrict__ bank,   // [4][32][64][27]
    const float* __restrict__ ws_in,  // alpha + s
    _Float16* __restrict__ wf) {
  const int b = blockIdx.x >> 5;
  const int o = blockIdx.x & 31;
  const int tid = threadIdx.x;
  __shared__ float red[256];

  float al[4];
#pragma unroll
  for (int n = 0; n < 4; ++n) al[n] = ws_in[WS_ALPHA + b * 4 + n];
  const float* sB = ws_in + WS_S + b * 64;

  float wv[7];
  float ss = 0.f;
#pragma unroll
  for (int r = 0; r < 7; ++r) {
    const int e = tid + r * 256;
    float v = 0.f;
    if (e < CIN_ * TAPS_) {
      const int i = e / TAPS_;
      const int t = e - i * TAPS_;
      const int base = (o * CIN_ + i) * TAPS_ + t;
      float bw = 0.f;
#pragma unroll
      for (int n = 0; n < 4; ++n)
        bw += al[n] * bank[base + n * (COUT_ * CIN_ * TAPS_)];
      v = bw * sB[i];
    }
    wv[r] = v;
    ss += v * v;
  }
  red[tid] = ss;
  __syncthreads();
  for (int st = 128; st > 0; st >>= 1) {
    if (tid < st) red[tid] += red[tid + st];
    __syncthreads();
  }
  const float demod = rsqrtf(red[0] + EPS_);

#pragma unroll
  for (int r = 0; r < 7; ++r) {
    const int e = tid + r * 256;
    if (e < CIN_ * TAPS_) {
      const int i = e / TAPS_;
      const int t = e - i * TAPS_;
      const int c = i >> 4, h = (i >> 3) & 1, j = i & 7;
      wf[((((b * 4 + c) * TAPS_ + t) * 2 + h) * 32 + o) * 8 + j] =
          (_Float16)(wv[r] * demod);
    }
  }
}

// ---------------------------------------------------------------------------
// Kernel 3: implicit-GEMM 3D conv via v_mfma_f32_32x32x16_f16.
// Workgroup (256 thr = 4 waves) computes a 2z x 4y x 32x voxel tile for all
// 32 output channels. K = 64 cin * 27 taps, chunked by 16 cin; within a
// chunk k = tap*16 + ii so each k-step (16) is one tap, 16 channels.
//   A (weights): lane l holds A[oc=l&31][k = (l>>5)*8 + j]  <- wl LDS, b128
//   B (x patch): lane l holds B[k][vox = l&31]              <- xs LDS, b128
//   D: col(vox)=l&31, row(oc)=(r&3)+8*(r>>2)+4*(l>>5)
// ---------------------------------------------------------------------------
__global__ __launch_bounds__(256, 2) void k_conv(
    const float* __restrict__ x,       // [4][64][32][32][32]
    const _Float16* __restrict__ wf,   // fragment-ordered f16 weights
    float* __restrict__ ws_y) {        // [4][32][32768]
  __shared__ __align__(16) _Float16 wl[CHUNK_HALVES_];   // 27648 B
  __shared__ __align__(16) _Float16 xs[2 * HALO_ * 8];   // 26112 B

  const int b = blockIdx.y;
  const int bx = blockIdx.x;           // [0,128)
  const int z0 = (bx >> 3) * 2;
  const int y0 = (bx & 7) * 4;
  const int tid = threadIdx.x;
  const int w = tid >> 6;              // wave 0..3
  const int lane = tid & 63;
  const int hf = lane >> 5;            // k-half
  const int col = lane & 31;           // voxel-in-row / oc column

  const int lz = w >> 1;               // wave's local z (0..1)
  const int ly0 = (w & 1) * 2;         // wave's local y base (0 or 2)

  floatx16 acc0, acc1;
#pragma unroll
  for (int i = 0; i < 16; ++i) { acc0[i] = 0.f; acc1[i] = 0.f; }

  const float* xb = x + (size_t)b * CIN_ * VOX_;

  for (int c = 0; c < 4; ++c) {
    __syncthreads();
    // ---- stage weights chunk (13824 halves = 1728 float4) ----
    {
      const float4* src = (const float4*)(wf + (size_t)(b * 4 + c) * CHUNK_HALVES_);
      float4* dst = (float4*)wl;
      for (int j = tid; j < 1728; j += 256) dst[j] = src[j];
    }
    // ---- stage x halo (816 voxels x 16 channels), f16, channel-contig ----
    {
      const int i0 = c * 16;
      for (int e = tid; e < HALO_ * 16; e += 256) {
        const int hv = e % HALO_;       // consecutive lanes -> consecutive hv
        const int ii = e / HALO_;
        const int xp = hv % 34;
        const int t2 = hv / 34;
        const int yp = t2 % 6;
        const int dzp = t2 / 6;
        const int gz = z0 + dzp - 1;
        const int gy = y0 + yp - 1;
        const int gx = xp - 1;
        float v = 0.f;
        if ((unsigned)gz < 32u && (unsigned)gy < 32u && (unsigned)gx < 32u)
          v = xb[(size_t)(i0 + ii) * VOX_ + gz * 1024 + gy * 32 + gx];
        xs[((ii >> 3) * HALO_ + hv) * 8 + (ii & 7)] = (_Float16)v;
      }
    }
    __syncthreads();

    // ---- MFMA k-loop: 27 taps ----
    const int xbase = hf * HALO_ + lz * 204 + ly0 * 34 + col;  // +const per tap
    const int wbase = (hf * 32 + col) * 8;
#pragma unroll
    for (int t = 0; t < TAPS_; ++t) {
      const int dz = t / 9, dy = (t / 3) % 3, dx = t % 3;
      const half8 af = *(const half8*)&wl[wbase + t * 512];
      const int hv0 = xbase + dz * 204 + dy * 34 + dx;
      const half8 b0 = *(const half8*)&xs[hv0 * 8];
      const half8 b1 = *(const half8*)&xs[(hv0 + 34) * 8];
      acc0 = __builtin_amdgcn_mfma_f32_32x32x16_f16(af, b0, acc0, 0, 0, 0);
      acc1 = __builtin_amdgcn_mfma_f32_32x32x16_f16(af, b1, acc1, 0, 0, 0);
    }
  }

  // ---- epilogue ----
  const int zz = z0 + lz;
  const int yy = y0 + ly0;
  float* yb = ws_y + (size_t)b * COUT_ * VOX_;
#pragma unroll
  for (int r = 0; r < 16; ++r) {
    const int oc = (r & 3) + 8 * (r >> 2) + 4 * hf;
    float* p = yb + (size_t)oc * VOX_ + zz * 1024 + yy * 32 + col;
    p[0] = acc0[r];
    p[32] = acc1[r];
  }
}

// ---------------------------------------------------------------------------
// Kernel 4: trilinear 2x upsample + 1x1x1 vox head. Thread computes an
// even/odd x-pair (shares the center bilinear sample), float2 stores.
// even out = 0.25*t[max(k-1,0)] + 0.75*t[k]
// odd  out = 0.75*t[k] + 0.25*t[min(k+1,31)]
// ---------------------------------------------------------------------------
__global__ __launch_bounds__(256) void k_up(
    const float* __restrict__ ws_y,   // [4][32][32768]
    const float* __restrict__ vox_w,  // [1][32]
    const float* __restrict__ vox_b,  // [1]
    float* __restrict__ out) {
  const int b = blockIdx.y;
  const int v = blockIdx.x * 256 + threadIdx.x;  // pair index, 0..131071
  const int k = v & 31;
  const int y = (v >> 5) & 63;
  const int z = v >> 11;

  const float sz = fmaxf(z * 0.5f - 0.25f, 0.f);
  const int z0 = (int)sz;
  const float wz = sz - (float)z0;
  const int z1 = min(z0 + 1, 31);

  const float sy = fmaxf(y * 0.5f - 0.25f, 0.f);
  const int yy0 = (int)sy;
  const float wy = sy - (float)yy0;
  const int yy1 = min(yy0 + 1, 31);

  const int xm = max(k - 1, 0);
  const int xp = min(k + 1, 31);

  const int r00 = z0 * 1024 + yy0 * 32;
  const int r01 = z0 * 1024 + yy1 * 32;
  const int r10 = z1 * 1024 + yy0 * 32;
  const int r11 = z1 * 1024 + yy1 * 32;

  const float c00 = (1.f - wz) * (1.f - wy);
  const float c01 = (1.f - wz) * wy;
  const float c10 = wz * (1.f - wy);
  const float c11 = wz * wy;

  const float* yb = ws_y + (size_t)b * COUT_ * VOX_;
  float* yup = out + OUT_YUP + (size_t)b * COUT_ * UPVOX_ + z * 4096 + y * 64 + 2 * k;
  const float vb = vox_b[0];

  float oa = 0.f, ob = 0.f;
  for (int o = 0; o < COUT_; ++o) {
    const float* yc = yb + (size_t)o * VOX_;
    const float tm = c00 * yc[r00 + xm] + c01 * yc[r01 + xm] +
                     c10 * yc[r10 + xm] + c11 * yc[r11 + xm];
    const float tc = c00 * yc[r00 + k] + c01 * yc[r01 + k] +
                     c10 * yc[r10 + k] + c11 * yc[r11 + k];
    const float tp = c00 * yc[r00 + xp] + c01 * yc[r01 + xp] +
                     c10 * yc[r10 + xp] + c11 * yc[r11 + xp];
    const float e0 = 0.25f * tm + 0.75f * tc;
    const float e1 = 0.75f * tc + 0.25f * tp;
    float2 st; st.x = e0; st.y = e1;
    *(float2*)(yup + (size_t)o * UPVOX_) = st;
    const float vw = vox_w[o];
    oa = fmaf(vw, e0, oa);
    ob = fmaf(vw, e1, ob);
  }
  float2 so; so.x = oa + vb; so.y = ob + vb;
  *(float2*)(out + OUT_VOX + (size_t)b * UPVOX_ + z * 4096 + y * 64 + 2 * k) = so;
}

// ---------------------------------------------------------------------------
extern "C" void kernel_launch(void* const* d_in, const int* in_sizes, int n_in,
                              void* d_out, int out_size, void* d_ws, size_t ws_size,
                              hipStream_t stream) {
  const float* x        = (const float*)d_in[0];
  const float* style    = (const float*)d_in[1];
  const float* bank     = (const float*)d_in[2];
  const float* affine_w = (const float*)d_in[3];
  const float* affine_b = (const float*)d_in[4];
  const float* sel_w    = (const float*)d_in[5];
  const float* sel_b    = (const float*)d_in[6];
  const float* vox_w    = (const float*)d_in[7];
  const float* vox_b    = (const float*)d_in[8];
  float* out = (float*)d_out;
  float* ws  = (float*)d_ws;
  _Float16* wf16 = (_Float16*)(ws + WS_WF16);
  float* ws_y = ws + WS_Y;

  k_style<<<1, 256, 0, stream>>>(style, affine_w, affine_b, sel_w, sel_b, ws);
  k_weights<<<128, 256, 0, stream>>>(bank, ws, wf16);
  k_conv<<<dim3(128, B_), 256, 0, stream>>>(x, wf16, ws_y);
  k_up<<<dim3(512, B_), 256, 0, stream>>>(ws_y, vox_w, vox_b, out);
}

// Round 5
// 233.378 us; speedup vs baseline: 2.6027x; 1.2831x over previous
//
#include <hip/hip_runtime.h>
#include <math.h>

// ---------------------------------------------------------------------------
// Problem constants
// ---------------------------------------------------------------------------
#define B_    4
#define CIN_  64
#define COUT_ 32
#define MOD_  128
#define VOX_  32768       // 32^3
#define UPVOX_ 262144     // 64^3
#define TAPS_ 27
#define EPS_  1e-8f

#define HALO_   1224      // 6z * 6y * 34x halo voxels per 4z*4y*32x block
#define XUNITS_ 2448      // 2 halves-of-16ch * HALO_  (16-byte units per chunk)
#define WUNITS_ 1728      // 13824 halves / 8          (16-byte units per chunk)
#define CHUNK_HALVES_ 13824  // 16 cin * 27 taps * 32 oc

// Workspace layout (in floats)
#define WS_ALPHA 0        // 16 floats  [b][n]
#define WS_S     16       // 256 floats [b][i]
#define WS_WF16  512      // f16 weights: 4b*4c*13824 halves
#define WS_Y     111104   // 4*32*32768 floats, conv output
#define WS_V32   4305408  // 4*32768 floats, vox head at 32^3

// Output layout (floats in d_out)
#define OUT_YUP  0
#define OUT_VOX  33554432

typedef _Float16 half8 __attribute__((ext_vector_type(8)));
typedef float floatx16 __attribute__((ext_vector_type(16)));

// ---------------------------------------------------------------------------
// Kernel 1: alpha = softmax(style@sel_w.T + sel_b); s = style@affine_w.T + b
// ---------------------------------------------------------------------------
__global__ __launch_bounds__(256) void k_style(
    const float* __restrict__ style,     // [4][128]
    const float* __restrict__ affine_w,  // [64][128]
    const float* __restrict__ affine_b,  // [64]
    const float* __restrict__ sel_w,     // [4][128]
    const float* __restrict__ sel_b,     // [4]
    float* __restrict__ ws) {
  __shared__ float lg[16];
  const int tid = threadIdx.x;

  if (tid < 16) {
    const int b = tid >> 2, n = tid & 3;
    float l = sel_b[n];
    for (int k = 0; k < MOD_; ++k) l += style[b * MOD_ + k] * sel_w[n * MOD_ + k];
    lg[tid] = l;
  }
  __syncthreads();
  if (tid < 16) {
    const int b = tid >> 2;
    const float m = fmaxf(fmaxf(lg[b * 4 + 0], lg[b * 4 + 1]),
                          fmaxf(lg[b * 4 + 2], lg[b * 4 + 3]));
    float den = 0.f;
    for (int j = 0; j < 4; ++j) den += expf(lg[b * 4 + j] - m);
    ws[WS_ALPHA + tid] = expf(lg[tid] - m) / den;
  }
  {
    const int b = tid >> 6, i = tid & 63;
    float v = affine_b[i];
    for (int k = 0; k < MOD_; ++k) v += style[b * MOD_ + k] * affine_w[i * MOD_ + k];
    ws[WS_S + tid] = v;
  }
}

// ---------------------------------------------------------------------------
// Kernel 2: mix bank + modulate + demodulate; emit f16 weights in MFMA
// A-fragment order: wf[b][chunk c][tap t][half h][oc][j], cin i = c*16+h*8+j.
// ---------------------------------------------------------------------------
__global__ __launch_bounds__(256) void k_weights(
    const float* __restrict__ bank,   // [4][32][64][27]
    const float* __restrict__ ws_in,
    _Float16* __restrict__ wf) {
  const int b = blockIdx.x >> 5;
  const int o = blockIdx.x & 31;
  const int tid = threadIdx.x;
  __shared__ float red[256];

  float al[4];
#pragma unroll
  for (int n = 0; n < 4; ++n) al[n] = ws_in[WS_ALPHA + b * 4 + n];
  const float* sB = ws_in + WS_S + b * 64;

  float wv[7];
  float ss = 0.f;
#pragma unroll
  for (int r = 0; r < 7; ++r) {
    const int e = tid + r * 256;
    float v = 0.f;
    if (e < CIN_ * TAPS_) {
      const int i = e / TAPS_;
      const int t = e - i * TAPS_;
      const int base = (o * CIN_ + i) * TAPS_ + t;
      float bw = 0.f;
#pragma unroll
      for (int n = 0; n < 4; ++n)
        bw += al[n] * bank[base + n * (COUT_ * CIN_ * TAPS_)];
      v = bw * sB[i];
    }
    wv[r] = v;
    ss += v * v;
  }
  red[tid] = ss;
  __syncthreads();
  for (int st = 128; st > 0; st >>= 1) {
    if (tid < st) red[tid] += red[tid + st];
    __syncthreads();
  }
  const float demod = rsqrtf(red[0] + EPS_);

#pragma unroll
  for (int r = 0; r < 7; ++r) {
    const int e = tid + r * 256;
    if (e < CIN_ * TAPS_) {
      const int i = e / TAPS_;
      const int t = e - i * TAPS_;
      const int c = i >> 4, h = (i >> 3) & 1, j = i & 7;
      wf[((((b * 4 + c) * TAPS_ + t) * 2 + h) * 32 + o) * 8 + j] =
          (_Float16)(wv[r] * demod);
    }
  }
}

// ---------------------------------------------------------------------------
// Kernel 2b: pack x (f32 NCDHW) -> xt (f16, [b][34][34][34][64], zero-pad).
// Thread unit = (xp, 8-channel group): 8 reads (fully clamped addresses,
// never OOB), one 16B store. Out-of-range taps multiplied to zero.
// xt lives in d_out scratch (k_up fully overwrites d_out afterwards).
// ---------------------------------------------------------------------------
__global__ __launch_bounds__(256) void k_pack(
    const float* __restrict__ x, _Float16* __restrict__ xt) {
  const int yp = blockIdx.x, zp = blockIdx.y, b = blockIdx.z;
  const int gz = zp - 1, gy = yp - 1;
  const bool zy_ok = ((unsigned)gz < 32u) && ((unsigned)gy < 32u);
  const int gzc = min(max(gz, 0), 31);
  const int gyc = min(max(gy, 0), 31);
  _Float16* dst = xt + (((size_t)(b * 34 + zp) * 34 + yp) * 34) * 64;
  const float* srow = x + ((size_t)b * CIN_) * VOX_ + gzc * 1024 + gyc * 32;
  for (int u = threadIdx.x; u < 34 * 8; u += 256) {
    const int xp = u >> 3, q = u & 7;
    const int gx = xp - 1;
    const bool ok = zy_ok && ((unsigned)gx < 32u);
    const float m = ok ? 1.0f : 0.0f;
    const int gxc = min(max(gx, 0), 31);
    half8 h;
#pragma unroll
    for (int i = 0; i < 8; ++i) {
      const float v = srow[(size_t)(q * 8 + i) * VOX_ + gxc];
      h[i] = (_Float16)(v * m);
    }
    *(half8*)&dst[xp * 64 + q * 8] = h;
  }
}

// ---------------------------------------------------------------------------
// Kernel 3: implicit-GEMM conv, mfma_f32_32x32x16_f16, double-buffered LDS,
// software-pipelined staging (global->VGPR for chunk c+1 in flight during
// compute(c); ds_write_b128 after; ONE barrier per chunk).
// Block = 4z*4y*32x (256 blocks = 1/CU), 4 waves of 2z*2y (4 accs each).
// Epilogue also computes v32 = vox_w . y (upsample commutes with 1x1 conv).
// ---------------------------------------------------------------------------
__global__ __launch_bounds__(256, 1) void k_conv(
    const _Float16* __restrict__ xt,   // [4][34][34][34][64]
    const _Float16* __restrict__ wf,   // [b][c][t][h][oc][8]
    const float* __restrict__ vox_w,   // [32]
    float* __restrict__ ws_y,          // [4][32][32768]
    float* __restrict__ v32) {         // [4][32768]
  __shared__ __align__(16) _Float16 wl[2][CHUNK_HALVES_];   // 55296 B
  __shared__ __align__(16) _Float16 xs[2][XUNITS_ * 8];     // 78336 B

  const int b  = blockIdx.y;
  const int bx = blockIdx.x;           // 64 blocks per batch
  const int z0 = (bx >> 3) * 4;
  const int y0 = (bx & 7) * 4;
  const int tid = threadIdx.x;
  const int w = tid >> 6;
  const int lane = tid & 63;
  const int hf = lane >> 5;
  const int col = lane & 31;
  const int wz = (w >> 1) * 2;         // wave z base in block (0/2)
  const int wy = (w & 1) * 2;          // wave y base in block (0/2)

  const _Float16* xtb = xt + (size_t)b * (34 * 34 * 34 * 64);
  const _Float16* wfb = wf + (size_t)b * 4 * CHUNK_HALVES_;

  // Per-lane x-halo staging offsets (in halves) for units u = j*256 + tid:
  // u -> h = u/HALO_, hv = u%HALO_; hv -> (hz,hy,hx) in 6*6*34.
  int xoff[10];
  bool xok[10];
#pragma unroll
  for (int j = 0; j < 10; ++j) {
    const int u = j * 256 + tid;
    xok[j] = (u < XUNITS_);
    const int uc = xok[j] ? u : 0;
    const int h = uc / HALO_, hv = uc - h * HALO_;
    const int hz = hv / 204;
    const int rem = hv - hz * 204;
    const int hy = rem / 34;
    const int hx = rem - hy * 34;
    xoff[j] = (((z0 + hz) * 34 + (y0 + hy)) * 34 + hx) * 64 + h * 8;
  }

  floatx16 acc[2][2];
#pragma unroll
  for (int az = 0; az < 2; ++az)
#pragma unroll
    for (int ay = 0; ay < 2; ++ay)
#pragma unroll
      for (int r = 0; r < 16; ++r) acc[az][ay][r] = 0.f;

  half8 wv[7], xv[10];

  auto load_chunk = [&](int c) {
    const _Float16* wsrc = wfb + (size_t)c * CHUNK_HALVES_;
#pragma unroll
    for (int j = 0; j < 7; ++j) {
      const int u = j * 256 + tid;
      wv[j] = *(const half8*)(wsrc + (size_t)(u < WUNITS_ ? u : 0) * 8);
    }
#pragma unroll
    for (int j = 0; j < 10; ++j)
      xv[j] = *(const half8*)(xtb + xoff[j] + c * 16);
  };
  auto write_chunk = [&](int bufi) {
#pragma unroll
    for (int j = 0; j < 7; ++j) {
      const int u = j * 256 + tid;
      if (u < WUNITS_) *(half8*)&wl[bufi][u * 8] = wv[j];
    }
#pragma unroll
    for (int j = 0; j < 10; ++j) {
      const int u = j * 256 + tid;
      if (xok[j]) *(half8*)&xs[bufi][u * 8] = xv[j];
    }
  };
  auto compute = [&](int bufi) {
    const _Float16* xb_ = xs[bufi];
    const _Float16* wb_ = wl[bufi];
#pragma unroll
    for (int dx = 0; dx < 3; ++dx) {
      half8 Bf[4][4];
#pragma unroll
      for (int zs = 0; zs < 4; ++zs)
#pragma unroll
        for (int ys = 0; ys < 4; ++ys) {
          const int hv = ((wz + zs) * 6 + (wy + ys)) * 34 + dx + col;
          Bf[zs][ys] = *(const half8*)&xb_[(hf * HALO_ + hv) * 8];
        }
#pragma unroll
      for (int dz = 0; dz < 3; ++dz)
#pragma unroll
        for (int dy = 0; dy < 3; ++dy) {
          const int t = (dz * 3 + dy) * 3 + dx;
          const half8 af = *(const half8*)&wb_[((t * 2 + hf) * 32 + col) * 8];
          acc[0][0] = __builtin_amdgcn_mfma_f32_32x32x16_f16(af, Bf[dz][dy], acc[0][0], 0, 0, 0);
          acc[0][1] = __builtin_amdgcn_mfma_f32_32x32x16_f16(af, Bf[dz][dy + 1], acc[0][1], 0, 0, 0);
          acc[1][0] = __builtin_amdgcn_mfma_f32_32x32x16_f16(af, Bf[dz + 1][dy], acc[1][0], 0, 0, 0);
          acc[1][1] = __builtin_amdgcn_mfma_f32_32x32x16_f16(af, Bf[dz + 1][dy + 1], acc[1][1], 0, 0, 0);
        }
    }
  };

  // Software pipeline: one barrier per chunk; writes of chunk c+1 go to the
  // other buffer, which no wave can be reading (barrier at end of c-1 ensures
  // all waves finished compute(c-1)).
  load_chunk(0);
  write_chunk(0);
  __syncthreads();
  for (int c = 0; c < 4; ++c) {
    if (c < 3) load_chunk(c + 1);
    compute(c & 1);
    if (c < 3) {
      write_chunk((c + 1) & 1);
      __syncthreads();
    }
  }

  // ---- epilogue: y stores + vox partial ----
  float vw[16];
#pragma unroll
  for (int r = 0; r < 16; ++r)
    vw[r] = vox_w[(r & 3) + 8 * (r >> 2) + 4 * hf];

  float* yb2 = ws_y + (size_t)b * COUT_ * VOX_;
#pragma unroll
  for (int az = 0; az < 2; ++az)
#pragma unroll
    for (int ay = 0; ay < 2; ++ay) {
      const int zz = z0 + wz + az, yy = y0 + wy + ay;
      const int vbase = zz * 1024 + yy * 32 + col;
      float p = 0.f;
#pragma unroll
      for (int r = 0; r < 16; ++r) {
        const int oc = (r & 3) + 8 * (r >> 2) + 4 * hf;
        yb2[(size_t)oc * VOX_ + vbase] = acc[az][ay][r];
        p = fmaf(vw[r], acc[az][ay][r], p);
      }
      p += __shfl_xor(p, 32);
      if (hf == 0) v32[((size_t)b << 15) + vbase] = p;
    }
}

// ---------------------------------------------------------------------------
// Kernel 4: trilinear 2x upsample from LDS-staged z-planes. Grid:
// (32 z-pairs, 33 "channels" [32 y + v32], 4 b). Thread -> 2z*2y*8x brick.
// ---------------------------------------------------------------------------
__global__ __launch_bounds__(256) void k_up(
    const float* __restrict__ ws_y,   // [4][32][32768]
    const float* __restrict__ v32,    // [4][32768]
    const float* __restrict__ vox_b,  // [1]
    float* __restrict__ out) {
  __shared__ float P[3][1056];        // 3 z-planes, row stride 33 (bank-safe)
  const int kz = blockIdx.x;          // z-pair 0..31
  const int ch = blockIdx.y;          // 0..32 (32 == vox head)
  const int b = blockIdx.z;

  const int pzm = max(kz - 1, 0), pzp = min(kz + 1, 31);
  const float* src = (ch < 32) ? (ws_y + (((size_t)(b * 32 + ch)) << 15))
                               : (v32 + ((size_t)b << 15));
  for (int j = threadIdx.x; j < 768; j += 256) {
    const int p = j >> 8, idx = j & 255;
    const int r = idx >> 3, q = (idx & 7) * 4;
    const int zsrc = (p == 0) ? pzm : ((p == 1) ? kz : pzp);
    const float4 v = *(const float4*)(src + (zsrc << 10) + r * 32 + q);
    float* dp = &P[p][r * 33 + q];
    dp[0] = v.x; dp[1] = v.y; dp[2] = v.z; dp[3] = v.w;
  }
  __syncthreads();

  const int yp = threadIdx.x >> 3;    // 0..31 (y-pair)
  const int xq = threadIdx.x & 7;     // 0..7  (8 out-x per thread)
  const int ym = max(yp - 1, 0) * 33, yc = yp * 33, ypp = min(yp + 1, 31) * 33;

  int gxi[6];
#pragma unroll
  for (int i = 0; i < 6; ++i) gxi[i] = min(max(4 * xq - 1 + i, 0), 31);

  float ry[3][2][6];
#pragma unroll
  for (int p = 0; p < 3; ++p)
#pragma unroll
    for (int i = 0; i < 6; ++i) {
      const float a = P[p][ym + gxi[i]];
      const float bb = P[p][yc + gxi[i]];
      const float cc = P[p][ypp + gxi[i]];
      ry[p][0][i] = fmaf(0.25f, a, 0.75f * bb);
      ry[p][1][i] = fmaf(0.25f, cc, 0.75f * bb);
    }

  const float vb = (ch == 32) ? vox_b[0] : 0.f;
  float* base = out + ((ch < 32) ? (OUT_YUP + (((size_t)(b * 32 + ch)) * UPVOX_))
                                 : (OUT_VOX + (size_t)b * UPVOX_)) +
                (size_t)(2 * kz) * 4096 + (2 * yp) * 64 + 8 * xq;

#pragma unroll
  for (int zo = 0; zo < 2; ++zo)
#pragma unroll
    for (int yo = 0; yo < 2; ++yo) {
      float s[6];
#pragma unroll
      for (int i = 0; i < 6; ++i)
        s[i] = zo == 0 ? fmaf(0.25f, ry[0][yo][i], 0.75f * ry[1][yo][i])
                       : fmaf(0.25f, ry[2][yo][i], 0.75f * ry[1][yo][i]);
      float o[8];
#pragma unroll
      for (int ox = 0; ox < 8; ++ox) {
        const int k = ox >> 1;
        o[ox] = (ox & 1) ? fmaf(0.25f, s[k + 2], 0.75f * s[k + 1])
                         : fmaf(0.25f, s[k], 0.75f * s[k + 1]);
        o[ox] += vb;
      }
      float4* dst = (float4*)(base + (size_t)zo * 4096 + yo * 64);
      float4 v0; v0.x = o[0]; v0.y = o[1]; v0.z = o[2]; v0.w = o[3];
      float4 v1; v1.x = o[4]; v1.y = o[5]; v1.z = o[6]; v1.w = o[7];
      dst[0] = v0;
      dst[1] = v1;
    }
}

// ---------------------------------------------------------------------------
extern "C" void kernel_launch(void* const* d_in, const int* in_sizes, int n_in,
                              void* d_out, int out_size, void* d_ws, size_t ws_size,
                              hipStream_t stream) {
  const float* x        = (const float*)d_in[0];
  const float* style    = (const float*)d_in[1];
  const float* bank     = (const float*)d_in[2];
  const float* affine_w = (const float*)d_in[3];
  const float* affine_b = (const float*)d_in[4];
  const float* sel_w    = (const float*)d_in[5];
  const float* sel_b    = (const float*)d_in[6];
  const float* vox_w    = (const float*)d_in[7];
  const float* vox_b    = (const float*)d_in[8];
  float* out = (float*)d_out;
  float* ws  = (float*)d_ws;
  _Float16* wf16 = (_Float16*)(ws + WS_WF16);
  float* ws_y = ws + WS_Y;
  float* v32  = ws + WS_V32;
  // xt scratch lives at the front of d_out; k_up overwrites all of d_out.
  _Float16* xt = (_Float16*)d_out;

  k_style<<<1, 256, 0, stream>>>(style, affine_w, affine_b, sel_w, sel_b, ws);
  k_weights<<<128, 256, 0, stream>>>(bank, ws, wf16);
  k_pack<<<dim3(34, 34, B_), 256, 0, stream>>>(x, xt);
  k_conv<<<dim3(64, B_), 256, 0, stream>>>(xt, wf16, vox_w, ws_y, v32);
  k_up<<<dim3(32, 33, B_), 256, 0, stream>>>(ws_y, v32, vox_b, out);
}